// Round 15
// baseline (130.971 us; speedup 1.0000x reference)
//
#include <hip/hip_runtime.h>
#include <hip/hip_bf16.h>

// Spatial Transformer: B=256, C=32, H=W=64. All fp32 in/out.
// R15: P1 reverted to R12 structure (R14's KC=1024 regressed) + bf16 partial (halved
// round-trip traffic) + DIAGNOSTIC double-launch of P3 (idempotent) to measure P3 directly.
//   k1 (1024 blocks): bf16 MFMA GEMM -> partial_bf16[256][1024][32] (d_ws, 16.8 MB).
//   k2 (256 blocks): reduce bf16 partial (64 KB contiguous/block) + MLP -> theta[256][8].
//   k3 (2048 blocks): affine grid + bilinear sample -> d_out.  (launched 2x: diagnostic)

#define K_TOT 131072
#define KC    256
#define PKN   1024                      // partial k-slots = 512 kc * 2 kh
#define STRB  ((size_t)PKN * 32)        // bf16 elements per batch row of partial (32768)

typedef short s16x8 __attribute__((ext_vector_type(8)));   // 8 bf16 in 4 VGPRs
typedef float f32x4 __attribute__((ext_vector_type(4)));

__device__ __forceinline__ short f2bf(float f) {
    return __builtin_bit_cast(short, __float2bfloat16(f));  // RNE; fuses to cvt_pk
}
__device__ __forceinline__ float bf2f(short s) {
    const unsigned u = ((unsigned)(unsigned short)s) << 16;
    return __builtin_bit_cast(float, u);
}

__device__ __forceinline__ s16x8 cvt8(float4 a, float4 b) {
    s16x8 r;
    r[0] = f2bf(a.x); r[1] = f2bf(a.y); r[2] = f2bf(a.z); r[3] = f2bf(a.w);
    r[4] = f2bf(b.x); r[5] = f2bf(b.y); r[6] = f2bf(b.z); r[7] = f2bf(b.w);
    return r;
}

__device__ __forceinline__ void gload_lds16(const float* g, float* l) {
    __builtin_amdgcn_global_load_lds(
        (const __attribute__((address_space(1))) void*)(g),
        (__attribute__((address_space(3))) void*)(l),
        16, 0, 0);   // dwordx4 direct-to-LDS; dest = wave-uniform base + lane*16
}

// ===================== k1 (R12 structure; bf16 partial stores) =====================
__global__ __launch_bounds__(256) void st_p1k(const float* __restrict__ x,
                                              const float* __restrict__ w1,
                                              __hip_bfloat16* __restrict__ partial) {
    __shared__ __align__(16) float xbuf[3][16 * KC];   // 3 x 16 KB, swizzled granules

    const int bid  = blockIdx.x;
    const int t    = threadIdx.x;
    const int wv   = t >> 6;
    const int lane = t & 63;
    const int m    = lane & 15;
    const int kb   = lane >> 4;
    const int jh   = wv & 1;                    // j half (16 j's)
    const int kh   = wv >> 1;                   // k half (128 k)

    const int xcd  = bid & 7;
    const int q    = bid >> 3;                  // 0..127
    const int kc   = xcd * 64 + (q >> 1);       // 0..511, contiguous per XCD
    const int half = q & 1;                     // batch half (128 rows)
    const size_t k0 = (size_t)kc * KC;

    // w fragments in registers: this wave's (jh, kh) quadrant, 4 frags.
    const float* wq = w1 + (size_t)(jh * 16 + m) * K_TOT + k0 + (size_t)kh * 128 + kb * 8;
    float4 wr[8];
#pragma unroll
    for (int sss = 0; sss < 4; ++sss) {
        wr[2 * sss]     = *(const float4*)(wq + sss * 32);
        wr[2 * sss + 1] = *(const float4*)(wq + sss * 32 + 4);
    }

    // prologue DMA: tiles 0 and 1 (depth-2). 4 instrs/wave/tile.
#pragma unroll
    for (int pt = 0; pt < 2; ++pt) {
#pragma unroll
        for (int i2 = 0; i2 < 4; ++i2) {
            const int r = wv * 4 + i2;
            const int b0 = half * 128 + pt * 16;
            const float* gsrc = x + (size_t)(b0 + r) * K_TOT + k0 + ((lane ^ (r & 7)) << 2);
            gload_lds16(gsrc, &xbuf[pt][r * KC]);
        }
    }

    s16x8 wf[4];
#pragma unroll
    for (int sss = 0; sss < 4; ++sss) wf[sss] = cvt8(wr[2 * sss], wr[2 * sss + 1]);

    const int pk = kc * 2 + kh;
    const int sw = m & 7;

    // vmcnt per iter (DMA[4] + 2 store-instr groups... stores now short: 4 per iter):
    // same counting as R12: it0 vmcnt(4); it1/it7 vmcnt(8); else vmcnt(12)
#pragma unroll
    for (int it = 0; it < 8; ++it) {
        if (it == 0)                 asm volatile("s_waitcnt vmcnt(4)"  ::: "memory");
        else if (it == 1 || it == 7) asm volatile("s_waitcnt vmcnt(8)"  ::: "memory");
        else                         asm volatile("s_waitcnt vmcnt(12)" ::: "memory");
        __builtin_amdgcn_s_barrier();           // raw barrier: no vmcnt(0) drain
        __builtin_amdgcn_sched_barrier(0);      // no ds_read hoisting above

        if (it + 2 < 8) {
            float* nbuf = xbuf[(it + 2) % 3];
            const int b0n = half * 128 + (it + 2) * 16;
#pragma unroll
            for (int i2 = 0; i2 < 4; ++i2) {
                const int r = wv * 4 + i2;
                const float* gsrc = x + (size_t)(b0n + r) * K_TOT + k0 + ((lane ^ (r & 7)) << 2);
                gload_lds16(gsrc, nbuf + r * KC);
            }
        }

        const float* xr = &xbuf[it % 3][m * KC];
        f32x4 acc = {0.f, 0.f, 0.f, 0.f};
#pragma unroll
        for (int sss = 0; sss < 4; ++sss) {
            const int gb = kh * 32 + sss * 8 + kb * 2;     // 16B granule index of k
            const float4 fa = *(const float4*)(xr + ((gb ^ sw) << 2));
            const float4 fb = *(const float4*)(xr + (((gb + 1) ^ sw) << 2));
            const s16x8 af = cvt8(fa, fb);
            acc = __builtin_amdgcn_mfma_f32_16x16x32_bf16(af, wf[sss], acc, 0, 0, 0);
        }

        // C/D: col(j)=m, row(b within 16)=kb*4+rr. partial[b][pk][j] (bf16).
        const int b0 = half * 128 + it * 16;
        __hip_bfloat16* p0 = partial + (size_t)(b0 + kb * 4) * STRB + (size_t)pk * 32 + jh * 16 + m;
#pragma unroll
        for (int rr = 0; rr < 4; ++rr)
            p0[(size_t)rr * STRB] = __float2bfloat16(acc[rr]);
    }
}

// ===================== k2 (bf16 partial stream) =====================
__global__ __launch_bounds__(256) void st_p2k(const __hip_bfloat16* __restrict__ partial,
                                              const float* __restrict__ b1,
                                              const float* __restrict__ w2,
                                              const float* __restrict__ b2,
                                              const float* __restrict__ w3,
                                              const float* __restrict__ b3,
                                              float* __restrict__ theta) {
    const int b = blockIdx.x;
    const int t = threadIdx.x;
    const s16x8* pb = (const s16x8*)(partial + (size_t)b * STRB);   // 64 KB contiguous

    // element j-class of thread t: j = (8t + e) & 31; constant over i (2048 % 32 == 0).
    float a8[8] = {0.f, 0.f, 0.f, 0.f, 0.f, 0.f, 0.f, 0.f};
#pragma unroll
    for (int i = 0; i < 16; ++i) {
        const s16x8 u = pb[i * 256 + t];
#pragma unroll
        for (int e = 0; e < 8; ++e) a8[e] += bf2f(u[e]);
    }

    __shared__ float red[256][8];
    __shared__ float s1s[32];
    __shared__ float s2s[32];
#pragma unroll
    for (int e = 0; e < 8; ++e) red[t][e] = a8[e];
    __syncthreads();
    // tree-reduce; off % 4 == 0 preserves the j-octet class (8*off % 32 == 0)
#pragma unroll
    for (int off = 128; off >= 4; off >>= 1) {
        if (t < off) {
#pragma unroll
            for (int e = 0; e < 8; ++e) red[t][e] += red[t + off][e];
        }
        __syncthreads();
    }
    if (t < 4) {                       // thread t holds j-octet 8t..8t+7
#pragma unroll
        for (int e = 0; e < 8; ++e)
            s1s[8 * t + e] = fmaxf(red[t][e] + b1[8 * t + e], 0.f);
    }
    __syncthreads();
    if (t < 32) {
        float vv = b2[t];
#pragma unroll
        for (int i = 0; i < 32; ++i) vv += w2[t * 32 + i] * s1s[i];
        s2s[t] = fmaxf(vv, 0.f);
    }
    __syncthreads();
    if (t < 8) {
        float vv = 0.f;
        if (t < 6) {
            vv = b3[t];
#pragma unroll
            for (int i = 0; i < 32; ++i) vv += w3[t * 32 + i] * s2s[i];
        }
        theta[b * 8 + t] = vv;
    }
}

// ===================== k3 =====================
__global__ __launch_bounds__(256) void st_p3k(const float* __restrict__ x,
                                              const float* __restrict__ theta,
                                              float* __restrict__ out) {
    const int bid = blockIdx.x;                 // 0..2047
    const int b   = bid >> 3;
    const int h0  = (bid & 7) * 8;
    const int t   = threadIdx.x;
    const int w   = t & 63;
    const int c0  = t >> 6;

    const float* tb = theta + b * 8;
    const float t0 = tb[0], t1 = tb[1], t2 = tb[2];
    const float t3 = tb[3], t4 = tb[4], t5 = tb[5];

    for (int r = 0; r < 8; ++r) {
        const int h = h0 + r;
        const float xs = ((float)w - 31.5f) * 0.03125f;
        const float ys = ((float)h - 31.5f) * 0.03125f;
        const float gxn = fmaf(t1, ys, fmaf(t0, xs, t2));
        const float gyn = fmaf(t4, ys, fmaf(t3, xs, t5));
        const float gx = fmaf(gxn, 32.f, 31.5f);
        const float gy = fmaf(gyn, 32.f, 31.5f);
        const float x0f = floorf(gx), y0f = floorf(gy);
        const float wx1 = gx - x0f, wx0 = 1.f - wx1;
        const float wy1 = gy - y0f, wy0 = 1.f - wy1;
        const int ix = (int)x0f, iy = (int)y0f;
        const bool vx0 = (ix >= 0) && (ix < 64);
        const bool vx1 = (ix >= -1) && (ix < 63);
        const bool vy0 = (iy >= 0) && (iy < 64);
        const bool vy1 = (iy >= -1) && (iy < 63);
        const int cx0 = min(max(ix, 0), 63);
        const int cx1 = min(max(ix + 1, 0), 63);
        const int cy0 = min(max(iy, 0), 63);
        const int cy1 = min(max(iy + 1, 0), 63);
        const float w00 = wx0 * wy0 * ((vx0 && vy0) ? 1.f : 0.f);
        const float w10 = wx1 * wy0 * ((vx1 && vy0) ? 1.f : 0.f);
        const float w01 = wx0 * wy1 * ((vx0 && vy1) ? 1.f : 0.f);
        const float w11 = wx1 * wy1 * ((vx1 && vy1) ? 1.f : 0.f);
        const int r0 = cy0 * 64, r1 = cy1 * 64;
#pragma unroll
        for (int i = 0; i < 8; ++i) {
            const int c = c0 + 4 * i;
            const float* img = x + (((size_t)b * 32 + c) << 12);
            const float v = w00 * img[r0 + cx0] + w10 * img[r0 + cx1]
                          + w01 * img[r1 + cx0] + w11 * img[r1 + cx1];
            __builtin_nontemporal_store(v, &out[(((size_t)b * 32 + c) << 12) + h * 64 + w]);
        }
    }
}

extern "C" void kernel_launch(void* const* d_in, const int* in_sizes, int n_in,
                              void* d_out, int out_size, void* d_ws, size_t ws_size,
                              hipStream_t stream) {
    const float* x  = (const float*)d_in[0];
    const float* w1 = (const float*)d_in[1];
    const float* b1 = (const float*)d_in[2];
    const float* w2 = (const float*)d_in[3];
    const float* b2 = (const float*)d_in[4];
    const float* w3 = (const float*)d_in[5];
    const float* b3 = (const float*)d_in[6];
    float* out = (float*)d_out;
    __hip_bfloat16* partial = (__hip_bfloat16*)d_ws;            // 16.8 MB
    float* theta = (float*)(partial + (size_t)256 * STRB);      // [256][8]

    st_p1k<<<1024, 256, 0, stream>>>(x, w1, partial);
    st_p2k<<<256, 256, 0, stream>>>(partial, b1, w2, b2, w3, b3, theta);
    st_p3k<<<2048, 256, 0, stream>>>(x, theta, out);
    st_p3k<<<2048, 256, 0, stream>>>(x, theta, out);   // diagnostic: dur delta = P3_warm
}

// Round 16
// 83.715 us; speedup vs baseline: 1.5645x; 1.5645x over previous
//
#include <hip/hip_runtime.h>
#include <hip/hip_bf16.h>

// Spatial Transformer: B=256, C=32, H=W=64. All fp32 in/out.
// R16: P3 gather optimization — corner-pair float2 loads (2 VMEM loads/elem instead of 4),
// weights remapped to pair slots (validity factorizes vx*vy). P1/P2 as R15 (bf16 partial).
//   k1 (1024 blocks): bf16 MFMA GEMM -> partial_bf16[256][1024][32] (d_ws, 16.8 MB).
//   k2 (256 blocks): reduce bf16 partial + MLP -> theta[256][8].
//   k3 (2048 blocks): affine grid + bilinear sample -> d_out (nt stores).

#define K_TOT 131072
#define KC    256
#define PKN   1024                      // partial k-slots = 512 kc * 2 kh
#define STRB  ((size_t)PKN * 32)        // bf16 elements per batch row of partial (32768)

typedef short s16x8 __attribute__((ext_vector_type(8)));   // 8 bf16 in 4 VGPRs
typedef float f32x4 __attribute__((ext_vector_type(4)));

struct __attribute__((aligned(4))) fpair { float a, b; };  // 4B-aligned 8B load

__device__ __forceinline__ short f2bf(float f) {
    return __builtin_bit_cast(short, __float2bfloat16(f));  // RNE; fuses to cvt_pk
}
__device__ __forceinline__ float bf2f(short s) {
    const unsigned u = ((unsigned)(unsigned short)s) << 16;
    return __builtin_bit_cast(float, u);
}

__device__ __forceinline__ s16x8 cvt8(float4 a, float4 b) {
    s16x8 r;
    r[0] = f2bf(a.x); r[1] = f2bf(a.y); r[2] = f2bf(a.z); r[3] = f2bf(a.w);
    r[4] = f2bf(b.x); r[5] = f2bf(b.y); r[6] = f2bf(b.z); r[7] = f2bf(b.w);
    return r;
}

__device__ __forceinline__ void gload_lds16(const float* g, float* l) {
    __builtin_amdgcn_global_load_lds(
        (const __attribute__((address_space(1))) void*)(g),
        (__attribute__((address_space(3))) void*)(l),
        16, 0, 0);   // dwordx4 direct-to-LDS; dest = wave-uniform base + lane*16
}

// ===================== k1 (R12 structure; bf16 partial stores) =====================
__global__ __launch_bounds__(256) void st_p1k(const float* __restrict__ x,
                                              const float* __restrict__ w1,
                                              __hip_bfloat16* __restrict__ partial) {
    __shared__ __align__(16) float xbuf[3][16 * KC];   // 3 x 16 KB, swizzled granules

    const int bid  = blockIdx.x;
    const int t    = threadIdx.x;
    const int wv   = t >> 6;
    const int lane = t & 63;
    const int m    = lane & 15;
    const int kb   = lane >> 4;
    const int jh   = wv & 1;                    // j half (16 j's)
    const int kh   = wv >> 1;                   // k half (128 k)

    const int xcd  = bid & 7;
    const int q    = bid >> 3;                  // 0..127
    const int kc   = xcd * 64 + (q >> 1);       // 0..511, contiguous per XCD
    const int half = q & 1;                     // batch half (128 rows)
    const size_t k0 = (size_t)kc * KC;

    // w fragments in registers: this wave's (jh, kh) quadrant, 4 frags.
    const float* wq = w1 + (size_t)(jh * 16 + m) * K_TOT + k0 + (size_t)kh * 128 + kb * 8;
    float4 wr[8];
#pragma unroll
    for (int sss = 0; sss < 4; ++sss) {
        wr[2 * sss]     = *(const float4*)(wq + sss * 32);
        wr[2 * sss + 1] = *(const float4*)(wq + sss * 32 + 4);
    }

    // prologue DMA: tiles 0 and 1 (depth-2). 4 instrs/wave/tile.
#pragma unroll
    for (int pt = 0; pt < 2; ++pt) {
#pragma unroll
        for (int i2 = 0; i2 < 4; ++i2) {
            const int r = wv * 4 + i2;
            const int b0 = half * 128 + pt * 16;
            const float* gsrc = x + (size_t)(b0 + r) * K_TOT + k0 + ((lane ^ (r & 7)) << 2);
            gload_lds16(gsrc, &xbuf[pt][r * KC]);
        }
    }

    s16x8 wf[4];
#pragma unroll
    for (int sss = 0; sss < 4; ++sss) wf[sss] = cvt8(wr[2 * sss], wr[2 * sss + 1]);

    const int pk = kc * 2 + kh;
    const int sw = m & 7;

    // vmcnt per iter: it0 vmcnt(4); it1/it7 vmcnt(8); else vmcnt(12)
#pragma unroll
    for (int it = 0; it < 8; ++it) {
        if (it == 0)                 asm volatile("s_waitcnt vmcnt(4)"  ::: "memory");
        else if (it == 1 || it == 7) asm volatile("s_waitcnt vmcnt(8)"  ::: "memory");
        else                         asm volatile("s_waitcnt vmcnt(12)" ::: "memory");
        __builtin_amdgcn_s_barrier();           // raw barrier: no vmcnt(0) drain
        __builtin_amdgcn_sched_barrier(0);      // no ds_read hoisting above

        if (it + 2 < 8) {
            float* nbuf = xbuf[(it + 2) % 3];
            const int b0n = half * 128 + (it + 2) * 16;
#pragma unroll
            for (int i2 = 0; i2 < 4; ++i2) {
                const int r = wv * 4 + i2;
                const float* gsrc = x + (size_t)(b0n + r) * K_TOT + k0 + ((lane ^ (r & 7)) << 2);
                gload_lds16(gsrc, nbuf + r * KC);
            }
        }

        const float* xr = &xbuf[it % 3][m * KC];
        f32x4 acc = {0.f, 0.f, 0.f, 0.f};
#pragma unroll
        for (int sss = 0; sss < 4; ++sss) {
            const int gb = kh * 32 + sss * 8 + kb * 2;     // 16B granule index of k
            const float4 fa = *(const float4*)(xr + ((gb ^ sw) << 2));
            const float4 fb = *(const float4*)(xr + (((gb + 1) ^ sw) << 2));
            const s16x8 af = cvt8(fa, fb);
            acc = __builtin_amdgcn_mfma_f32_16x16x32_bf16(af, wf[sss], acc, 0, 0, 0);
        }

        // C/D: col(j)=m, row(b within 16)=kb*4+rr. partial[b][pk][j] (bf16).
        const int b0 = half * 128 + it * 16;
        __hip_bfloat16* p0 = partial + (size_t)(b0 + kb * 4) * STRB + (size_t)pk * 32 + jh * 16 + m;
#pragma unroll
        for (int rr = 0; rr < 4; ++rr)
            p0[(size_t)rr * STRB] = __float2bfloat16(acc[rr]);
    }
}

// ===================== k2 (bf16 partial stream) =====================
__global__ __launch_bounds__(256) void st_p2k(const __hip_bfloat16* __restrict__ partial,
                                              const float* __restrict__ b1,
                                              const float* __restrict__ w2,
                                              const float* __restrict__ b2,
                                              const float* __restrict__ w3,
                                              const float* __restrict__ b3,
                                              float* __restrict__ theta) {
    const int b = blockIdx.x;
    const int t = threadIdx.x;
    const s16x8* pb = (const s16x8*)(partial + (size_t)b * STRB);   // 64 KB contiguous

    float a8[8] = {0.f, 0.f, 0.f, 0.f, 0.f, 0.f, 0.f, 0.f};
#pragma unroll
    for (int i = 0; i < 16; ++i) {                 // j-octet class of t constant over i
        const s16x8 u = pb[i * 256 + t];
#pragma unroll
        for (int e = 0; e < 8; ++e) a8[e] += bf2f(u[e]);
    }

    __shared__ float red[256][8];
    __shared__ float s1s[32];
    __shared__ float s2s[32];
#pragma unroll
    for (int e = 0; e < 8; ++e) red[t][e] = a8[e];
    __syncthreads();
#pragma unroll
    for (int off = 128; off >= 4; off >>= 1) {     // off%4==0 preserves j-octet class
        if (t < off) {
#pragma unroll
            for (int e = 0; e < 8; ++e) red[t][e] += red[t + off][e];
        }
        __syncthreads();
    }
    if (t < 4) {                                   // thread t holds j-octet 8t..8t+7
#pragma unroll
        for (int e = 0; e < 8; ++e)
            s1s[8 * t + e] = fmaxf(red[t][e] + b1[8 * t + e], 0.f);
    }
    __syncthreads();
    if (t < 32) {
        float vv = b2[t];
#pragma unroll
        for (int i = 0; i < 32; ++i) vv += w2[t * 32 + i] * s1s[i];
        s2s[t] = fmaxf(vv, 0.f);
    }
    __syncthreads();
    if (t < 8) {
        float vv = 0.f;
        if (t < 6) {
            vv = b3[t];
#pragma unroll
            for (int i = 0; i < 32; ++i) vv += w3[t * 32 + i] * s2s[i];
        }
        theta[b * 8 + t] = vv;
    }
}

// ===================== k3 (pair-load gathers) =====================
__global__ __launch_bounds__(256) void st_p3k(const float* __restrict__ x,
                                              const float* __restrict__ theta,
                                              float* __restrict__ out) {
    const int bid = blockIdx.x;                 // 0..2047
    const int b   = bid >> 3;
    const int h0  = (bid & 7) * 8;
    const int t   = threadIdx.x;
    const int w   = t & 63;
    const int c0  = t >> 6;

    const float* tb = theta + b * 8;
    const float t0 = tb[0], t1 = tb[1], t2 = tb[2];
    const float t3 = tb[3], t4 = tb[4], t5 = tb[5];

    for (int r = 0; r < 8; ++r) {
        const int h = h0 + r;
        const float xs = ((float)w - 31.5f) * 0.03125f;
        const float ys = ((float)h - 31.5f) * 0.03125f;
        const float gxn = fmaf(t1, ys, fmaf(t0, xs, t2));
        const float gyn = fmaf(t4, ys, fmaf(t3, xs, t5));
        const float gx = fmaf(gxn, 32.f, 31.5f);
        const float gy = fmaf(gyn, 32.f, 31.5f);
        const float x0f = floorf(gx), y0f = floorf(gy);
        const float wx1 = gx - x0f, wx0 = 1.f - wx1;
        const float wy1 = gy - y0f, wy0 = 1.f - wy1;
        const int ix = (int)x0f, iy = (int)y0f;

        // x-weights (with x-validity folded) mapped onto the pair slots at base bx
        const float wx0v = wx0 * ((ix >= 0 && ix < 64) ? 1.f : 0.f);
        const float wx1v = wx1 * ((ix >= -1 && ix < 63) ? 1.f : 0.f);
        const int bx = min(max(ix, 0), 62);
        float wxa, wxb;
        if (ix == bx)     { wxa = wx0v; wxb = wx1v; }   // interior
        else if (ix < bx) { wxa = wx1v; wxb = 0.f; }    // left clamp (ix=-1): slot a is col 0 = cx1
        else              { wxa = 0.f;  wxb = wx0v; }   // right clamp (ix=63): slot b is col 63 = cx0

        // y-weights with y-validity folded
        const float wy0v = wy0 * ((iy >= 0 && iy < 64) ? 1.f : 0.f);
        const float wy1v = wy1 * ((iy >= -1 && iy < 63) ? 1.f : 0.f);
        const int r0 = min(max(iy, 0), 63) * 64 + bx;
        const int r1 = min(max(iy + 1, 0), 63) * 64 + bx;

#pragma unroll
        for (int i = 0; i < 8; ++i) {
            const int c = c0 + 4 * i;
            const float* img = x + (((size_t)b * 32 + c) << 12);
            const fpair f0 = *(const fpair*)(img + r0);
            const fpair f1 = *(const fpair*)(img + r1);
            const float v = wy0v * (wxa * f0.a + wxb * f0.b)
                          + wy1v * (wxa * f1.a + wxb * f1.b);
            __builtin_nontemporal_store(v, &out[(((size_t)b * 32 + c) << 12) + h * 64 + w]);
        }
    }
}

extern "C" void kernel_launch(void* const* d_in, const int* in_sizes, int n_in,
                              void* d_out, int out_size, void* d_ws, size_t ws_size,
                              hipStream_t stream) {
    const float* x  = (const float*)d_in[0];
    const float* w1 = (const float*)d_in[1];
    const float* b1 = (const float*)d_in[2];
    const float* w2 = (const float*)d_in[3];
    const float* b2 = (const float*)d_in[4];
    const float* w3 = (const float*)d_in[5];
    const float* b3 = (const float*)d_in[6];
    float* out = (float*)d_out;
    __hip_bfloat16* partial = (__hip_bfloat16*)d_ws;            // 16.8 MB
    float* theta = (float*)(partial + (size_t)256 * STRB);      // [256][8]

    st_p1k<<<1024, 256, 0, stream>>>(x, w1, partial);
    st_p2k<<<256, 256, 0, stream>>>(partial, b1, w2, b2, w3, b3, theta);
    st_p3k<<<2048, 256, 0, stream>>>(x, theta, out);
}

// Round 17
// 80.551 us; speedup vs baseline: 1.6259x; 1.0393x over previous
//
#include <hip/hip_runtime.h>
#include <hip/hip_bf16.h>

// Spatial Transformer: B=256, C=32, H=W=64. All fp32 in/out.
// R17: P3 re-tiled for sequential writes — block = (b, 4-channel group); weights per (h,w)
// in registers (hq outer), c inner -> each store burst is 1 KB contiguous, c-planes written
// as ascending sequential streams. P1/P2 as R16 (bf16 partial).
//   k1 (1024 blocks): bf16 MFMA GEMM -> partial_bf16[256][1024][32] (d_ws, 16.8 MB).
//   k2 (256 blocks): reduce bf16 partial + MLP -> theta[256][8].
//   k3 (2048 blocks): affine grid + bilinear sample -> d_out (nt stores, sequential).

#define K_TOT 131072
#define KC    256
#define PKN   1024                      // partial k-slots = 512 kc * 2 kh
#define STRB  ((size_t)PKN * 32)        // bf16 elements per batch row of partial (32768)

typedef short s16x8 __attribute__((ext_vector_type(8)));   // 8 bf16 in 4 VGPRs
typedef float f32x4 __attribute__((ext_vector_type(4)));

struct __attribute__((aligned(4))) fpair { float a, b; };  // 4B-aligned 8B load

__device__ __forceinline__ short f2bf(float f) {
    return __builtin_bit_cast(short, __float2bfloat16(f));  // RNE; fuses to cvt_pk
}
__device__ __forceinline__ float bf2f(short s) {
    const unsigned u = ((unsigned)(unsigned short)s) << 16;
    return __builtin_bit_cast(float, u);
}

__device__ __forceinline__ s16x8 cvt8(float4 a, float4 b) {
    s16x8 r;
    r[0] = f2bf(a.x); r[1] = f2bf(a.y); r[2] = f2bf(a.z); r[3] = f2bf(a.w);
    r[4] = f2bf(b.x); r[5] = f2bf(b.y); r[6] = f2bf(b.z); r[7] = f2bf(b.w);
    return r;
}

__device__ __forceinline__ void gload_lds16(const float* g, float* l) {
    __builtin_amdgcn_global_load_lds(
        (const __attribute__((address_space(1))) void*)(g),
        (__attribute__((address_space(3))) void*)(l),
        16, 0, 0);   // dwordx4 direct-to-LDS; dest = wave-uniform base + lane*16
}

// ===================== k1 (R12 structure; bf16 partial stores) =====================
__global__ __launch_bounds__(256) void st_p1k(const float* __restrict__ x,
                                              const float* __restrict__ w1,
                                              __hip_bfloat16* __restrict__ partial) {
    __shared__ __align__(16) float xbuf[3][16 * KC];   // 3 x 16 KB, swizzled granules

    const int bid  = blockIdx.x;
    const int t    = threadIdx.x;
    const int wv   = t >> 6;
    const int lane = t & 63;
    const int m    = lane & 15;
    const int kb   = lane >> 4;
    const int jh   = wv & 1;                    // j half (16 j's)
    const int kh   = wv >> 1;                   // k half (128 k)

    const int xcd  = bid & 7;
    const int q    = bid >> 3;                  // 0..127
    const int kc   = xcd * 64 + (q >> 1);       // 0..511, contiguous per XCD
    const int half = q & 1;                     // batch half (128 rows)
    const size_t k0 = (size_t)kc * KC;

    // w fragments in registers: this wave's (jh, kh) quadrant, 4 frags.
    const float* wq = w1 + (size_t)(jh * 16 + m) * K_TOT + k0 + (size_t)kh * 128 + kb * 8;
    float4 wr[8];
#pragma unroll
    for (int sss = 0; sss < 4; ++sss) {
        wr[2 * sss]     = *(const float4*)(wq + sss * 32);
        wr[2 * sss + 1] = *(const float4*)(wq + sss * 32 + 4);
    }

    // prologue DMA: tiles 0 and 1 (depth-2). 4 instrs/wave/tile.
#pragma unroll
    for (int pt = 0; pt < 2; ++pt) {
#pragma unroll
        for (int i2 = 0; i2 < 4; ++i2) {
            const int r = wv * 4 + i2;
            const int b0 = half * 128 + pt * 16;
            const float* gsrc = x + (size_t)(b0 + r) * K_TOT + k0 + ((lane ^ (r & 7)) << 2);
            gload_lds16(gsrc, &xbuf[pt][r * KC]);
        }
    }

    s16x8 wf[4];
#pragma unroll
    for (int sss = 0; sss < 4; ++sss) wf[sss] = cvt8(wr[2 * sss], wr[2 * sss + 1]);

    const int pk = kc * 2 + kh;
    const int sw = m & 7;

    // vmcnt per iter: it0 vmcnt(4); it1/it7 vmcnt(8); else vmcnt(12)
#pragma unroll
    for (int it = 0; it < 8; ++it) {
        if (it == 0)                 asm volatile("s_waitcnt vmcnt(4)"  ::: "memory");
        else if (it == 1 || it == 7) asm volatile("s_waitcnt vmcnt(8)"  ::: "memory");
        else                         asm volatile("s_waitcnt vmcnt(12)" ::: "memory");
        __builtin_amdgcn_s_barrier();           // raw barrier: no vmcnt(0) drain
        __builtin_amdgcn_sched_barrier(0);      // no ds_read hoisting above

        if (it + 2 < 8) {
            float* nbuf = xbuf[(it + 2) % 3];
            const int b0n = half * 128 + (it + 2) * 16;
#pragma unroll
            for (int i2 = 0; i2 < 4; ++i2) {
                const int r = wv * 4 + i2;
                const float* gsrc = x + (size_t)(b0n + r) * K_TOT + k0 + ((lane ^ (r & 7)) << 2);
                gload_lds16(gsrc, nbuf + r * KC);
            }
        }

        const float* xr = &xbuf[it % 3][m * KC];
        f32x4 acc = {0.f, 0.f, 0.f, 0.f};
#pragma unroll
        for (int sss = 0; sss < 4; ++sss) {
            const int gb = kh * 32 + sss * 8 + kb * 2;     // 16B granule index of k
            const float4 fa = *(const float4*)(xr + ((gb ^ sw) << 2));
            const float4 fb = *(const float4*)(xr + (((gb + 1) ^ sw) << 2));
            const s16x8 af = cvt8(fa, fb);
            acc = __builtin_amdgcn_mfma_f32_16x16x32_bf16(af, wf[sss], acc, 0, 0, 0);
        }

        // C/D: col(j)=m, row(b within 16)=kb*4+rr. partial[b][pk][j] (bf16).
        const int b0 = half * 128 + it * 16;
        __hip_bfloat16* p0 = partial + (size_t)(b0 + kb * 4) * STRB + (size_t)pk * 32 + jh * 16 + m;
#pragma unroll
        for (int rr = 0; rr < 4; ++rr)
            p0[(size_t)rr * STRB] = __float2bfloat16(acc[rr]);
    }
}

// ===================== k2 (bf16 partial stream) =====================
__global__ __launch_bounds__(256) void st_p2k(const __hip_bfloat16* __restrict__ partial,
                                              const float* __restrict__ b1,
                                              const float* __restrict__ w2,
                                              const float* __restrict__ b2,
                                              const float* __restrict__ w3,
                                              const float* __restrict__ b3,
                                              float* __restrict__ theta) {
    const int b = blockIdx.x;
    const int t = threadIdx.x;
    const s16x8* pb = (const s16x8*)(partial + (size_t)b * STRB);   // 64 KB contiguous

    float a8[8] = {0.f, 0.f, 0.f, 0.f, 0.f, 0.f, 0.f, 0.f};
#pragma unroll
    for (int i = 0; i < 16; ++i) {                 // j-octet class of t constant over i
        const s16x8 u = pb[i * 256 + t];
#pragma unroll
        for (int e = 0; e < 8; ++e) a8[e] += bf2f(u[e]);
    }

    __shared__ float red[256][8];
    __shared__ float s1s[32];
    __shared__ float s2s[32];
#pragma unroll
    for (int e = 0; e < 8; ++e) red[t][e] = a8[e];
    __syncthreads();
#pragma unroll
    for (int off = 128; off >= 4; off >>= 1) {     // off%4==0 preserves j-octet class
        if (t < off) {
#pragma unroll
            for (int e = 0; e < 8; ++e) red[t][e] += red[t + off][e];
        }
        __syncthreads();
    }
    if (t < 4) {                                   // thread t holds j-octet 8t..8t+7
#pragma unroll
        for (int e = 0; e < 8; ++e)
            s1s[8 * t + e] = fmaxf(red[t][e] + b1[8 * t + e], 0.f);
    }
    __syncthreads();
    if (t < 32) {
        float vv = b2[t];
#pragma unroll
        for (int i = 0; i < 32; ++i) vv += w2[t * 32 + i] * s1s[i];
        s2s[t] = fmaxf(vv, 0.f);
    }
    __syncthreads();
    if (t < 8) {
        float vv = 0.f;
        if (t < 6) {
            vv = b3[t];
#pragma unroll
            for (int i = 0; i < 32; ++i) vv += w3[t * 32 + i] * s2s[i];
        }
        theta[b * 8 + t] = vv;
    }
}

// ===================== k3 (sequential-write tiling) =====================
// Block = (b, cgrp): c in {4*cgrp .. 4*cgrp+3}. Thread t: hsub = t>>6, w = t&63.
// hq outer (16): weights for (h = hq*4+hsub, w) computed once into registers;
// c inner (4): 2 pair-gathers + fma + nt store. Stores per (hq,c): threads write
// out[b][c][hq*4 .. hq*4+3][*] = 1024 B contiguous -> 4 ascending sequential streams/block.
__global__ __launch_bounds__(256) void st_p3k(const float* __restrict__ x,
                                              const float* __restrict__ theta,
                                              float* __restrict__ out) {
    const int bid  = blockIdx.x;                // 0..2047
    const int b    = bid >> 3;
    const int cgrp = bid & 7;
    const int t    = threadIdx.x;
    const int w    = t & 63;
    const int hsub = t >> 6;

    const float* tb = theta + b * 8;
    const float t0 = tb[0], t1 = tb[1], t2 = tb[2];
    const float t3 = tb[3], t4 = tb[4], t5 = tb[5];

    const float* xb  = x   + ((size_t)(b * 32 + cgrp * 4) << 12);
    float*       ob  = out + ((size_t)(b * 32 + cgrp * 4) << 12);

    for (int hq = 0; hq < 16; ++hq) {
        const int h = hq * 4 + hsub;
        const float xs = ((float)w - 31.5f) * 0.03125f;
        const float ys = ((float)h - 31.5f) * 0.03125f;
        const float gxn = fmaf(t1, ys, fmaf(t0, xs, t2));
        const float gyn = fmaf(t4, ys, fmaf(t3, xs, t5));
        const float gx = fmaf(gxn, 32.f, 31.5f);
        const float gy = fmaf(gyn, 32.f, 31.5f);
        const float x0f = floorf(gx), y0f = floorf(gy);
        const float wx1 = gx - x0f, wx0 = 1.f - wx1;
        const float wy1 = gy - y0f, wy0 = 1.f - wy1;
        const int ix = (int)x0f, iy = (int)y0f;

        // x-weights (x-validity folded) mapped onto pair slots at base bx
        const float wx0v = wx0 * ((ix >= 0 && ix < 64) ? 1.f : 0.f);
        const float wx1v = wx1 * ((ix >= -1 && ix < 63) ? 1.f : 0.f);
        const int bx = min(max(ix, 0), 62);
        float wxa, wxb;
        if (ix == bx)     { wxa = wx0v; wxb = wx1v; }   // interior
        else if (ix < bx) { wxa = wx1v; wxb = 0.f; }    // left clamp: slot a = col 0 = cx1
        else              { wxa = 0.f;  wxb = wx0v; }   // right clamp: slot b = col 63 = cx0

        const float wy0v = wy0 * ((iy >= 0 && iy < 64) ? 1.f : 0.f);
        const float wy1v = wy1 * ((iy >= -1 && iy < 63) ? 1.f : 0.f);
        const int r0 = min(max(iy, 0), 63) * 64 + bx;
        const int r1 = min(max(iy + 1, 0), 63) * 64 + bx;

        const int off = h * 64 + w;
#pragma unroll
        for (int ci = 0; ci < 4; ++ci) {
            const float* img = xb + ((size_t)ci << 12);
            const fpair f0 = *(const fpair*)(img + r0);
            const fpair f1 = *(const fpair*)(img + r1);
            const float v = wy0v * (wxa * f0.a + wxb * f0.b)
                          + wy1v * (wxa * f1.a + wxb * f1.b);
            __builtin_nontemporal_store(v, ob + ((size_t)ci << 12) + off);
        }
    }
}

extern "C" void kernel_launch(void* const* d_in, const int* in_sizes, int n_in,
                              void* d_out, int out_size, void* d_ws, size_t ws_size,
                              hipStream_t stream) {
    const float* x  = (const float*)d_in[0];
    const float* w1 = (const float*)d_in[1];
    const float* b1 = (const float*)d_in[2];
    const float* w2 = (const float*)d_in[3];
    const float* b2 = (const float*)d_in[4];
    const float* w3 = (const float*)d_in[5];
    const float* b3 = (const float*)d_in[6];
    float* out = (float*)d_out;
    __hip_bfloat16* partial = (__hip_bfloat16*)d_ws;            // 16.8 MB
    float* theta = (float*)(partial + (size_t)256 * STRB);      // [256][8]

    st_p1k<<<1024, 256, 0, stream>>>(x, w1, partial);
    st_p2k<<<256, 256, 0, stream>>>(partial, b1, w2, b2, w3, b3, theta);
    st_p3k<<<2048, 256, 0, stream>>>(x, theta, out);
}

// Round 18
// 77.061 us; speedup vs baseline: 1.6996x; 1.0453x over previous
//
#include <hip/hip_runtime.h>
#include <hip/hip_bf16.h>

// Spatial Transformer: B=256, C=32, H=W=64. All fp32 in/out.
// R18: P1 LDS cut to 32 KB (2x16 KB dbuf, counted vmcnt, 2 raw barriers/iter) -> 4 blocks/CU,
// no dispatch tail (48 KB gave 3/CU = 768 slots for 1024 blocks -> 1.33x tail penalty).
// P3 grid 4096 (8 hq per block) for more write-stream TLP. P2 as R17 (bf16 partial).
//   k1 (1024 blocks): bf16 MFMA GEMM -> partial_bf16[256][1024][32] (d_ws, 16.8 MB).
//   k2 (256 blocks): reduce bf16 partial + MLP -> theta[256][8].
//   k3 (4096 blocks): affine grid + bilinear sample -> d_out (nt stores, sequential).

#define K_TOT 131072
#define KC    256
#define PKN   1024                      // partial k-slots = 512 kc * 2 kh
#define STRB  ((size_t)PKN * 32)        // bf16 elements per batch row of partial (32768)

typedef short s16x8 __attribute__((ext_vector_type(8)));   // 8 bf16 in 4 VGPRs
typedef float f32x4 __attribute__((ext_vector_type(4)));

struct __attribute__((aligned(4))) fpair { float a, b; };  // 4B-aligned 8B load

__device__ __forceinline__ short f2bf(float f) {
    return __builtin_bit_cast(short, __float2bfloat16(f));  // RNE; fuses to cvt_pk
}
__device__ __forceinline__ float bf2f(short s) {
    const unsigned u = ((unsigned)(unsigned short)s) << 16;
    return __builtin_bit_cast(float, u);
}

__device__ __forceinline__ s16x8 cvt8(float4 a, float4 b) {
    s16x8 r;
    r[0] = f2bf(a.x); r[1] = f2bf(a.y); r[2] = f2bf(a.z); r[3] = f2bf(a.w);
    r[4] = f2bf(b.x); r[5] = f2bf(b.y); r[6] = f2bf(b.z); r[7] = f2bf(b.w);
    return r;
}

__device__ __forceinline__ void gload_lds16(const float* g, float* l) {
    __builtin_amdgcn_global_load_lds(
        (const __attribute__((address_space(1))) void*)(g),
        (__attribute__((address_space(3))) void*)(l),
        16, 0, 0);   // dwordx4 direct-to-LDS; dest = wave-uniform base + lane*16
}

// ===================== k1 (2x16 KB dbuf, counted vmcnt, 4 blocks/CU) =====================
// Decode: xcd = bid&7, q = bid>>3; kc = xcd*64 + (q>>1); half = q&1.
__global__ __launch_bounds__(256) void st_p1k(const float* __restrict__ x,
                                              const float* __restrict__ w1,
                                              __hip_bfloat16* __restrict__ partial) {
    __shared__ __align__(16) float xbuf[2][16 * KC];   // 2 x 16 KB, swizzled granules

    const int bid  = blockIdx.x;
    const int t    = threadIdx.x;
    const int wv   = t >> 6;
    const int lane = t & 63;
    const int m    = lane & 15;
    const int kb   = lane >> 4;
    const int jh   = wv & 1;                    // j half (16 j's)
    const int kh   = wv >> 1;                   // k half (128 k)

    const int xcd  = bid & 7;
    const int q    = bid >> 3;                  // 0..127
    const int kc   = xcd * 64 + (q >> 1);       // 0..511, contiguous per XCD
    const int half = q & 1;                     // batch half (128 rows)
    const size_t k0 = (size_t)kc * KC;

    // w fragments in registers: this wave's (jh, kh) quadrant, 4 frags.
    const float* wq = w1 + (size_t)(jh * 16 + m) * K_TOT + k0 + (size_t)kh * 128 + kb * 8;
    float4 wr[8];
#pragma unroll
    for (int sss = 0; sss < 4; ++sss) {
        wr[2 * sss]     = *(const float4*)(wq + sss * 32);
        wr[2 * sss + 1] = *(const float4*)(wq + sss * 32 + 4);
    }

    // prologue DMA: tile 0 -> buf0.
#pragma unroll
    for (int i2 = 0; i2 < 4; ++i2) {
        const int r = wv * 4 + i2;
        const int b0 = half * 128;
        const float* gsrc = x + (size_t)(b0 + r) * K_TOT + k0 + ((lane ^ (r & 7)) << 2);
        gload_lds16(gsrc, &xbuf[0][r * KC]);
    }

    s16x8 wf[4];
#pragma unroll
    for (int sss = 0; sss < 4; ++sss) wf[sss] = cvt8(wr[2 * sss], wr[2 * sss + 1]);

    const int pk = kc * 2 + kh;
    const int sw = m & 7;

    // Per-wave in-order VMEM stream: D0, D1, st0, D2, st1, D3, st2, ... , D7, st6, st7.
    // Before compute(it): after issuing D(it+1), outstanding <= D(it)+st(it-1)+D(it+1) = 12;
    // wait vmcnt(8) -> D(it) retired. it=0: only D0,D1 -> vmcnt(4). it=7: D7,st6 -> vmcnt(4).
#pragma unroll
    for (int it = 0; it < 8; ++it) {
        // issue D(it+1) into the other buffer; its readers (compute(it-1)) passed the
        // end-of-iteration barrier below.
        if (it + 1 < 8) {
            const int b0n = half * 128 + (it + 1) * 16;
#pragma unroll
            for (int i2 = 0; i2 < 4; ++i2) {
                const int r = wv * 4 + i2;
                const float* gsrc = x + (size_t)(b0n + r) * K_TOT + k0 + ((lane ^ (r & 7)) << 2);
                gload_lds16(gsrc, &xbuf[(it + 1) & 1][r * KC]);
            }
        }
        if (it == 0 || it == 7) asm volatile("s_waitcnt vmcnt(4)" ::: "memory");
        else                    asm volatile("s_waitcnt vmcnt(8)" ::: "memory");
        __builtin_amdgcn_s_barrier();           // everyone's D(it) complete
        __builtin_amdgcn_sched_barrier(0);      // no ds_read hoisting above

        const float* xr = &xbuf[it & 1][m * KC];
        f32x4 acc = {0.f, 0.f, 0.f, 0.f};
#pragma unroll
        for (int sss = 0; sss < 4; ++sss) {
            const int gb = kh * 32 + sss * 8 + kb * 2;     // 16B granule index of k
            const float4 fa = *(const float4*)(xr + ((gb ^ sw) << 2));
            const float4 fb = *(const float4*)(xr + (((gb + 1) ^ sw) << 2));
            const s16x8 af = cvt8(fa, fb);
            acc = __builtin_amdgcn_mfma_f32_16x16x32_bf16(af, wf[sss], acc, 0, 0, 0);
        }

        // C/D: col(j)=m, row(b within 16)=kb*4+rr. partial[b][pk][j] (bf16).
        const int b0 = half * 128 + it * 16;
        __hip_bfloat16* p0 = partial + (size_t)(b0 + kb * 4) * STRB + (size_t)pk * 32 + jh * 16 + m;
#pragma unroll
        for (int rr = 0; rr < 4; ++rr)
            p0[(size_t)rr * STRB] = __float2bfloat16(acc[rr]);

        __builtin_amdgcn_s_barrier();           // readers of xbuf[it&1] done -> D(it+2) may overwrite
    }
}

// ===================== k2 (bf16 partial stream) =====================
__global__ __launch_bounds__(256) void st_p2k(const __hip_bfloat16* __restrict__ partial,
                                              const float* __restrict__ b1,
                                              const float* __restrict__ w2,
                                              const float* __restrict__ b2,
                                              const float* __restrict__ w3,
                                              const float* __restrict__ b3,
                                              float* __restrict__ theta) {
    const int b = blockIdx.x;
    const int t = threadIdx.x;
    const s16x8* pb = (const s16x8*)(partial + (size_t)b * STRB);   // 64 KB contiguous

    float a8[8] = {0.f, 0.f, 0.f, 0.f, 0.f, 0.f, 0.f, 0.f};
#pragma unroll
    for (int i = 0; i < 16; ++i) {                 // j-octet class of t constant over i
        const s16x8 u = pb[i * 256 + t];
#pragma unroll
        for (int e = 0; e < 8; ++e) a8[e] += bf2f(u[e]);
    }

    __shared__ float red[256][8];
    __shared__ float s1s[32];
    __shared__ float s2s[32];
#pragma unroll
    for (int e = 0; e < 8; ++e) red[t][e] = a8[e];
    __syncthreads();
#pragma unroll
    for (int off = 128; off >= 4; off >>= 1) {     // off%4==0 preserves j-octet class
        if (t < off) {
#pragma unroll
            for (int e = 0; e < 8; ++e) red[t][e] += red[t + off][e];
        }
        __syncthreads();
    }
    if (t < 4) {                                   // thread t holds j-octet 8t..8t+7
#pragma unroll
        for (int e = 0; e < 8; ++e)
            s1s[8 * t + e] = fmaxf(red[t][e] + b1[8 * t + e], 0.f);
    }
    __syncthreads();
    if (t < 32) {
        float vv = b2[t];
#pragma unroll
        for (int i = 0; i < 32; ++i) vv += w2[t * 32 + i] * s1s[i];
        s2s[t] = fmaxf(vv, 0.f);
    }
    __syncthreads();
    if (t < 8) {
        float vv = 0.f;
        if (t < 6) {
            vv = b3[t];
#pragma unroll
            for (int i = 0; i < 32; ++i) vv += w3[t * 32 + i] * s2s[i];
        }
        theta[b * 8 + t] = vv;
    }
}

// ===================== k3 (sequential writes, 4096 blocks) =====================
// Block = (b, cgrp, hh): c in {4*cgrp..4*cgrp+3}, hq in {hh*8..hh*8+7}.
// Thread t: hsub = t>>6, w = t&63. Per (hq,c): 1 KB contiguous store burst.
__global__ __launch_bounds__(256) void st_p3k(const float* __restrict__ x,
                                              const float* __restrict__ theta,
                                              float* __restrict__ out) {
    const int bid  = blockIdx.x;                // 0..4095
    const int b    = bid >> 4;
    const int cgrp = (bid >> 1) & 7;
    const int hh   = bid & 1;
    const int t    = threadIdx.x;
    const int w    = t & 63;
    const int hsub = t >> 6;

    const float* tb = theta + b * 8;
    const float t0 = tb[0], t1 = tb[1], t2 = tb[2];
    const float t3 = tb[3], t4 = tb[4], t5 = tb[5];

    const float* xb = x   + ((size_t)(b * 32 + cgrp * 4) << 12);
    float*       ob = out + ((size_t)(b * 32 + cgrp * 4) << 12);

    for (int hq = hh * 8; hq < hh * 8 + 8; ++hq) {
        const int h = hq * 4 + hsub;
        const float xs = ((float)w - 31.5f) * 0.03125f;
        const float ys = ((float)h - 31.5f) * 0.03125f;
        const float gxn = fmaf(t1, ys, fmaf(t0, xs, t2));
        const float gyn = fmaf(t4, ys, fmaf(t3, xs, t5));
        const float gx = fmaf(gxn, 32.f, 31.5f);
        const float gy = fmaf(gyn, 32.f, 31.5f);
        const float x0f = floorf(gx), y0f = floorf(gy);
        const float wx1 = gx - x0f, wx0 = 1.f - wx1;
        const float wy1 = gy - y0f, wy0 = 1.f - wy1;
        const int ix = (int)x0f, iy = (int)y0f;

        // x-weights (x-validity folded) mapped onto pair slots at base bx
        const float wx0v = wx0 * ((ix >= 0 && ix < 64) ? 1.f : 0.f);
        const float wx1v = wx1 * ((ix >= -1 && ix < 63) ? 1.f : 0.f);
        const int bx = min(max(ix, 0), 62);
        float wxa, wxb;
        if (ix == bx)     { wxa = wx0v; wxb = wx1v; }   // interior
        else if (ix < bx) { wxa = wx1v; wxb = 0.f; }    // left clamp: slot a = col 0 = cx1
        else              { wxa = 0.f;  wxb = wx0v; }   // right clamp: slot b = col 63 = cx0

        const float wy0v = wy0 * ((iy >= 0 && iy < 64) ? 1.f : 0.f);
        const float wy1v = wy1 * ((iy >= -1 && iy < 63) ? 1.f : 0.f);
        const int r0 = min(max(iy, 0), 63) * 64 + bx;
        const int r1 = min(max(iy + 1, 0), 63) * 64 + bx;

        const int off = h * 64 + w;
#pragma unroll
        for (int ci = 0; ci < 4; ++ci) {
            const float* img = xb + ((size_t)ci << 12);
            const fpair f0 = *(const fpair*)(img + r0);
            const fpair f1 = *(const fpair*)(img + r1);
            const float v = wy0v * (wxa * f0.a + wxb * f0.b)
                          + wy1v * (wxa * f1.a + wxb * f1.b);
            __builtin_nontemporal_store(v, ob + ((size_t)ci << 12) + off);
        }
    }
}

extern "C" void kernel_launch(void* const* d_in, const int* in_sizes, int n_in,
                              void* d_out, int out_size, void* d_ws, size_t ws_size,
                              hipStream_t stream) {
    const float* x  = (const float*)d_in[0];
    const float* w1 = (const float*)d_in[1];
    const float* b1 = (const float*)d_in[2];
    const float* w2 = (const float*)d_in[3];
    const float* b2 = (const float*)d_in[4];
    const float* w3 = (const float*)d_in[5];
    const float* b3 = (const float*)d_in[6];
    float* out = (float*)d_out;
    __hip_bfloat16* partial = (__hip_bfloat16*)d_ws;            // 16.8 MB
    float* theta = (float*)(partial + (size_t)256 * STRB);      // [256][8]

    st_p1k<<<1024, 256, 0, stream>>>(x, w1, partial);
    st_p2k<<<256, 256, 0, stream>>>(partial, b1, w2, b2, w3, b3, theta);
    st_p3k<<<4096, 256, 0, stream>>>(x, theta, out);
}